// Round 6
// baseline (29.308 us; speedup 1.0000x reference)
//
#include <hip/hip_runtime.h>

// Problem: x:[B=64,S=2048,K=256] f32, W:[K=256,D=512] f32
// out[b,d] = mean_s(x) @ W  -> [64,512] f32
// Stage A: seq-reduce x into [B,CHUNKS,K] partials. 128 MiB streaming read —
// batch-8 in-flight f32x4 loads per thread (MLP: 128B/thread outstanding vs
// ~96B when the allocator serializes at VGPR=32). Stage B: mean + tiny GEMM.

typedef float f32x4 __attribute__((ext_vector_type(4)));

#define BB 64
#define SS 2048
#define KK 256
#define DD 512
#define CHUNKS 16
#define RPC (SS / CHUNKS)  // 128 rows per chunk

// Stage A: one block per (b, chunk). 256 threads = 64 f32x4 lanes across K
// x 4 rows in s; 32 row-iterations per thread in 4 batches of 8.
__global__ __launch_bounds__(256, 4) void partial_sum_kernel(const float* __restrict__ x,
                                                             float* __restrict__ part) {
    const int blk = blockIdx.x;          // b * CHUNKS + c
    const int b  = blk >> 4;
    const int c  = blk & 15;
    const int t  = threadIdx.x;
    const int tx = t & 63;               // f32x4 index across K (64*4 = 256)
    const int ty = t >> 6;               // 0..3

    const f32x4* xp = (const f32x4*)(x + ((size_t)b * SS + (size_t)c * RPC) * KK) + tx;

    f32x4 acc = {0.f, 0.f, 0.f, 0.f};
    #pragma unroll
    for (int g = 0; g < 4; ++g) {
        f32x4 v0 = xp[(size_t)((g * 32 +  0) + ty) * (KK / 4)];
        f32x4 v1 = xp[(size_t)((g * 32 +  4) + ty) * (KK / 4)];
        f32x4 v2 = xp[(size_t)((g * 32 +  8) + ty) * (KK / 4)];
        f32x4 v3 = xp[(size_t)((g * 32 + 12) + ty) * (KK / 4)];
        f32x4 v4 = xp[(size_t)((g * 32 + 16) + ty) * (KK / 4)];
        f32x4 v5 = xp[(size_t)((g * 32 + 20) + ty) * (KK / 4)];
        f32x4 v6 = xp[(size_t)((g * 32 + 24) + ty) * (KK / 4)];
        f32x4 v7 = xp[(size_t)((g * 32 + 28) + ty) * (KK / 4)];
        acc += ((v0 + v1) + (v2 + v3)) + ((v4 + v5) + (v6 + v7));
    }

    __shared__ f32x4 smem[4][64];
    smem[ty][tx] = acc;
    __syncthreads();

    if (ty == 0) {
        f32x4 r = (smem[0][tx] + smem[1][tx]) + (smem[2][tx] + smem[3][tx]);
        ((f32x4*)(part + ((size_t)b * CHUNKS + c) * KK))[tx] = r;
    }
}

// Stage B: 4 blocks per b. Block (b,dq): 128 output cols (32 f32x4),
// split-k 8-way across thread groups, LDS reduce, store.
__global__ __launch_bounds__(256) void finish_kernel(const float* __restrict__ part,
                                                     const float* __restrict__ w,
                                                     float* __restrict__ out) {
    const int b  = blockIdx.x >> 2;
    const int dq = blockIdx.x & 3;
    const int t  = threadIdx.x;          // 0..255

    __shared__ float xm[KK];
    {
        float s = 0.f;
        const float* pp = part + (size_t)b * CHUNKS * KK + t;
        #pragma unroll
        for (int c = 0; c < CHUNKS; ++c) s += pp[c * KK];       // fixed order
        xm[t] = s * (1.0f / SS);
    }
    __syncthreads();

    const int col4 = dq * 32 + (t & 31); // f32x4 column in [0, 128)
    const int kg   = t >> 5;             // k-group 0..7, 32 k's each
    const f32x4* w4 = (const f32x4*)w;

    f32x4 acc = {0.f, 0.f, 0.f, 0.f};
    #pragma unroll
    for (int kk = 0; kk < 32; ++kk) {
        const int k = kg * 32 + kk;
        acc += xm[k] * w4[(size_t)k * (DD / 4) + col4];         // 16B coalesced
    }

    __shared__ f32x4 red[8][32];
    if (kg) red[kg][t & 31] = acc;
    __syncthreads();
    if (kg == 0) {
        #pragma unroll
        for (int g = 1; g < 8; ++g) acc += red[g][t];
        ((f32x4*)out)[(size_t)b * (DD / 4) + col4] = acc;
    }
}

extern "C" void kernel_launch(void* const* d_in, const int* in_sizes, int n_in,
                              void* d_out, int out_size, void* d_ws, size_t ws_size,
                              hipStream_t stream) {
    const float* x = (const float*)d_in[0];
    const float* w = (const float*)d_in[1];
    float* out  = (float*)d_out;
    float* part = (float*)d_ws;   // B*CHUNKS*K floats = 1 MiB

    partial_sum_kernel<<<BB * CHUNKS, 256, 0, stream>>>(x, part);
    finish_kernel<<<BB * 4, 256, 0, stream>>>(part, w, out);
}

// Round 7
// 28.977 us; speedup vs baseline: 1.0114x; 1.0114x over previous
//
#include <hip/hip_runtime.h>

// Problem: x:[B=64,S=2048,K=256] f32, W:[K=256,D=512] f32
// out[b,d] = mean_s(x) @ W  -> [64,512] f32
// Stage A: seq-reduce x into [B,32,K] partials (128 MiB streaming read,
// HBM-bound; plain cached f32x4 loads — best measured). CHUNKS=32 for finer
// tail granularity. Stage B: 256 blocks, split-k 8, f32x4 W loads.

typedef float f32x4 __attribute__((ext_vector_type(4)));

#define BB 64
#define SS 2048
#define KK 256
#define DD 512
#define CHUNKS 32
#define RPC (SS / CHUNKS)  // 64 rows per chunk

// Stage A: one block per (b, chunk). 256 threads = 64 f32x4 lanes across K
// x 4 rows in s; 16 row-iterations per thread.
__global__ __launch_bounds__(256) void partial_sum_kernel(const float* __restrict__ x,
                                                          float* __restrict__ part) {
    const int blk = blockIdx.x;          // b * CHUNKS + c
    const int b  = blk >> 5;
    const int c  = blk & 31;
    const int t  = threadIdx.x;
    const int tx = t & 63;               // f32x4 index across K (64*4 = 256)
    const int ty = t >> 6;               // 0..3

    const f32x4* xp = (const f32x4*)(x + ((size_t)b * SS + (size_t)c * RPC) * KK) + tx;

    f32x4 acc = {0.f, 0.f, 0.f, 0.f};
    #pragma unroll
    for (int i = 0; i < RPC / 4; ++i)
        acc += xp[(size_t)(i * 4 + ty) * (KK / 4)];

    __shared__ f32x4 smem[4][64];
    smem[ty][tx] = acc;
    __syncthreads();

    if (ty == 0) {
        f32x4 r = (smem[0][tx] + smem[1][tx]) + (smem[2][tx] + smem[3][tx]);
        ((f32x4*)(part + ((size_t)b * CHUNKS + c) * KK))[tx] = r;
    }
}

// Stage B: 4 blocks per b. Block (b,dq): 128 output cols (32 f32x4),
// split-k 8-way across thread groups, LDS reduce, store.
__global__ __launch_bounds__(256) void finish_kernel(const float* __restrict__ part,
                                                     const float* __restrict__ w,
                                                     float* __restrict__ out) {
    const int b  = blockIdx.x >> 2;
    const int dq = blockIdx.x & 3;
    const int t  = threadIdx.x;          // 0..255

    __shared__ float xm[KK];
    {
        float s = 0.f;
        const float* pp = part + (size_t)b * CHUNKS * KK + t;
        #pragma unroll
        for (int c = 0; c < CHUNKS; ++c) s += pp[c * KK];       // fixed order
        xm[t] = s * (1.0f / SS);
    }
    __syncthreads();

    const int col4 = dq * 32 + (t & 31); // f32x4 column in [0, 128)
    const int kg   = t >> 5;             // k-group 0..7, 32 k's each
    const f32x4* w4 = (const f32x4*)w;

    f32x4 acc = {0.f, 0.f, 0.f, 0.f};
    #pragma unroll
    for (int kk = 0; kk < 32; ++kk) {
        const int k = kg * 32 + kk;
        acc += xm[k] * w4[(size_t)k * (DD / 4) + col4];         // 16B coalesced
    }

    __shared__ f32x4 red[8][32];
    if (kg) red[kg][t & 31] = acc;
    __syncthreads();
    if (kg == 0) {
        #pragma unroll
        for (int g = 1; g < 8; ++g) acc += red[g][t];
        ((f32x4*)out)[(size_t)b * (DD / 4) + col4] = acc;
    }
}

extern "C" void kernel_launch(void* const* d_in, const int* in_sizes, int n_in,
                              void* d_out, int out_size, void* d_ws, size_t ws_size,
                              hipStream_t stream) {
    const float* x = (const float*)d_in[0];
    const float* w = (const float*)d_in[1];
    float* out  = (float*)d_out;
    float* part = (float*)d_ws;   // B*CHUNKS*K floats = 2 MiB

    partial_sum_kernel<<<BB * CHUNKS, 256, 0, stream>>>(x, part);
    finish_kernel<<<BB * 4, 256, 0, stream>>>(part, w, out);
}

// Round 8
// 28.295 us; speedup vs baseline: 1.0358x; 1.0241x over previous
//
#include <hip/hip_runtime.h>

// Problem: x:[B=64,S=2048,K=256] f32, W:[K=256,D=512] f32
// out[b,d] = mean_s(x) @ W  -> [64,512] f32
// Stage A: seq-reduce x into [B,16,K] partials (128 MiB streaming read,
// HBM-bound). XCD-contiguous block swizzle: 1024 blocks / 8 XCDs -> each XCD
// streams one contiguous ~16.8 MB partition of x (DRAM/fabric locality)
// instead of 128 KB round-robin fragments. Fully-resident grid (4 blk/CU).
// Stage B: 256 blocks, split-k 8, f32x4 W loads (W L2-hot).

typedef float f32x4 __attribute__((ext_vector_type(4)));

#define BB 64
#define SS 2048
#define KK 256
#define DD 512
#define CHUNKS 16
#define RPC (SS / CHUNKS)   // 128 rows per chunk
#define NBLK (BB * CHUNKS)  // 1024
#define NXCD 8

// Stage A: one (virtual) block per (b, chunk). 256 threads = 64 f32x4 lanes
// across K x 4 rows in s; 32 row-iterations per thread.
__global__ __launch_bounds__(256) void partial_sum_kernel(const float* __restrict__ x,
                                                          float* __restrict__ part) {
    // XCD-contiguous swizzle: hw blocks round-robin over 8 XCDs; give XCD i
    // the contiguous virtual range [i*128, (i+1)*128). NBLK % NXCD == 0.
    const int virt = (blockIdx.x & (NXCD - 1)) * (NBLK / NXCD) + (blockIdx.x >> 3);
    const int b  = virt >> 4;            // / CHUNKS
    const int c  = virt & 15;            // % CHUNKS
    const int t  = threadIdx.x;
    const int tx = t & 63;               // f32x4 index across K (64*4 = 256)
    const int ty = t >> 6;               // 0..3

    const f32x4* xp = (const f32x4*)(x + ((size_t)b * SS + (size_t)c * RPC) * KK) + tx;

    f32x4 acc = {0.f, 0.f, 0.f, 0.f};
    #pragma unroll
    for (int i = 0; i < RPC / 4; ++i)
        acc += xp[(size_t)(i * 4 + ty) * (KK / 4)];

    __shared__ f32x4 smem[4][64];
    smem[ty][tx] = acc;
    __syncthreads();

    if (ty == 0) {
        f32x4 r = (smem[0][tx] + smem[1][tx]) + (smem[2][tx] + smem[3][tx]);
        ((f32x4*)(part + ((size_t)b * CHUNKS + c) * KK))[tx] = r;
    }
}

// Stage B: 4 blocks per b. Block (b,dq): 128 output cols (32 f32x4),
// split-k 8-way across thread groups, LDS reduce, store.
__global__ __launch_bounds__(256) void finish_kernel(const float* __restrict__ part,
                                                     const float* __restrict__ w,
                                                     float* __restrict__ out) {
    const int b  = blockIdx.x >> 2;
    const int dq = blockIdx.x & 3;
    const int t  = threadIdx.x;          // 0..255

    __shared__ float xm[KK];
    {
        float s = 0.f;
        const float* pp = part + (size_t)b * CHUNKS * KK + t;
        #pragma unroll
        for (int c = 0; c < CHUNKS; ++c) s += pp[c * KK];       // fixed order
        xm[t] = s * (1.0f / SS);
    }
    __syncthreads();

    const int col4 = dq * 32 + (t & 31); // f32x4 column in [0, 128)
    const int kg   = t >> 5;             // k-group 0..7, 32 k's each
    const f32x4* w4 = (const f32x4*)w;

    f32x4 acc = {0.f, 0.f, 0.f, 0.f};
    #pragma unroll
    for (int kk = 0; kk < 32; ++kk) {
        const int k = kg * 32 + kk;
        acc += xm[k] * w4[(size_t)k * (DD / 4) + col4];         // 16B coalesced
    }

    __shared__ f32x4 red[8][32];
    if (kg) red[kg][t & 31] = acc;
    __syncthreads();
    if (kg == 0) {
        #pragma unroll
        for (int g = 1; g < 8; ++g) acc += red[g][t];
        ((f32x4*)out)[(size_t)b * (DD / 4) + col4] = acc;
    }
}

extern "C" void kernel_launch(void* const* d_in, const int* in_sizes, int n_in,
                              void* d_out, int out_size, void* d_ws, size_t ws_size,
                              hipStream_t stream) {
    const float* x = (const float*)d_in[0];
    const float* w = (const float*)d_in[1];
    float* out  = (float*)d_out;
    float* part = (float*)d_ws;   // B*CHUNKS*K floats = 1 MiB

    partial_sum_kernel<<<NBLK, 256, 0, stream>>>(x, part);
    finish_kernel<<<BB * 4, 256, 0, stream>>>(part, w, out);
}